// Round 4
// baseline (1313.206 us; speedup 1.0000x reference)
//
#include <hip/hip_runtime.h>

// ---------------------------------------------------------------------------
// STN pipeline, theta chain in FP64 (must match np float64 reference: sampler
// has floor() discontinuities at coord==223 with O(100..1000) jumps; any f32
// noise upstream of theta flips floors -> fails. f64 of ANY summation order
// lands ~1e-13 from the np value -> flip set identical -> absmax stays ~73).
//
// R4 changes: conv weights now live in SGPRs (scalar loads of f64 weights
// pre-converted by k_prep) instead of LDS -- removes ~1000 ds_read/thread
// that made both convs latency-bound (VALUBusy 14.5%). conv2 oc-split
// (blockIdx&1, wave-uniform) doubles the grid. Vector float2/double2 window
// loads. No LDS in conv kernels at all.
// ---------------------------------------------------------------------------

// Convert conv weights/biases f32 -> f64 once.
// dst: [0..1175] c1w, [1176..1183] c1b, [1184..3183] c2w, [3184..3193] c2b
__global__ __launch_bounds__(256) void k_prep(
    const float* __restrict__ c1w, const float* __restrict__ c1b,
    const float* __restrict__ c2w, const float* __restrict__ c2b,
    double* __restrict__ dst) {
  int i = blockIdx.x * 256 + threadIdx.x;
  if (i < 1176) dst[i] = (double)c1w[i];
  else if (i < 1184) dst[i] = (double)c1b[i - 1176];
  else if (i < 3184) dst[i] = (double)c2w[i - 1184];
  else if (i < 3194) dst[i] = (double)c2b[i - 3184];
}

// conv1 + relu + maxpool : in (64,224,224,3) f32 -> out (64,109,109,8) f64
// Weights via wave-uniform scalar loads (SGPR). Window kept in f32 VGPRs,
// promoted to f64 right before the FMA (4 cvt per 32 FMA).
__global__ __launch_bounds__(256) void k_conv1(
    const float* __restrict__ in, const double* __restrict__ wq,
    double* __restrict__ out) {
  const double* w64 = wq;          // 1176 conv1 weights, HWIO
  const double* b64 = wq + 1176;   // 8 biases

  int idx = blockIdx.x * 256 + threadIdx.x;
  if (idx >= 64 * 109 * 109) return;
  int px = idx % 109;
  int t  = idx / 109;
  int py = t % 109;
  int b  = t / 109;

  double acc[2][2][8];
#pragma unroll
  for (int i = 0; i < 2; ++i)
#pragma unroll
    for (int j = 0; j < 2; ++j)
#pragma unroll
      for (int k = 0; k < 8; ++k) acc[i][j][k] = 0.0;

  const float* ibase = in + ((size_t)(b * 224 + 2 * py) * 224 + 2 * px) * 3;

  for (int ky = 0; ky < 7; ++ky) {
    const float2* r0 = reinterpret_cast<const float2*>(ibase + ky * 672);
    const float2* r1 = reinterpret_cast<const float2*>(ibase + (ky + 1) * 672);
    float a0[24], a1[24];
#pragma unroll
    for (int j = 0; j < 12; ++j) {
      float2 u = r0[j]; a0[2 * j] = u.x; a0[2 * j + 1] = u.y;
      float2 v = r1[j]; a1[2 * j] = v.x; a1[2 * j + 1] = v.y;
    }
#pragma unroll
    for (int kx = 0; kx < 7; ++kx) {
#pragma unroll
      for (int c = 0; c < 3; ++c) {
        double v00 = (double)a0[kx * 3 + c];
        double v01 = (double)a0[kx * 3 + 3 + c];
        double v10 = (double)a1[kx * 3 + c];
        double v11 = (double)a1[kx * 3 + 3 + c];
        const double* wp = &w64[((ky * 7 + kx) * 3 + c) * 8];
#pragma unroll
        for (int oc = 0; oc < 8; ++oc) {
          double wv = wp[oc];  // uniform index -> s_load, SGPR operand
          acc[0][0][oc] = fma(v00, wv, acc[0][0][oc]);
          acc[0][1][oc] = fma(v01, wv, acc[0][1][oc]);
          acc[1][0][oc] = fma(v10, wv, acc[1][0][oc]);
          acc[1][1][oc] = fma(v11, wv, acc[1][1][oc]);
        }
      }
    }
  }

  double* op = out + (size_t)idx * 8;
#pragma unroll
  for (int oc = 0; oc < 8; ++oc) {
    double m = fmax(fmax(acc[0][0][oc], acc[0][1][oc]),
                    fmax(acc[1][0][oc], acc[1][1][oc]));
    op[oc] = fmax(m + b64[oc], 0.0);
  }
}

// conv2 + relu + maxpool : in (64,109,109,8) f64 -> out (64,52,52,10) f64
// oc half selected by blockIdx&1 (wave-uniform -> weights stay in SGPRs).
__global__ __launch_bounds__(256) void k_conv2(
    const double* __restrict__ in, const double* __restrict__ wq,
    double* __restrict__ out) {
  const double* w64 = wq + 1184;   // 2000 conv2 weights, HWIO (5,5,8,10)
  const double* b64 = wq + 3184;   // 10 biases

  int oh = blockIdx.x & 1;                       // oc half: 0..4 / 5..9
  int idx = (blockIdx.x >> 1) * 256 + threadIdx.x;
  if (idx >= 64 * 52 * 52) return;
  int px = idx % 52;
  int t  = idx / 52;
  int py = t % 52;
  int b  = t / 52;

  double acc[2][2][5];
#pragma unroll
  for (int i = 0; i < 2; ++i)
#pragma unroll
    for (int j = 0; j < 2; ++j)
#pragma unroll
      for (int k = 0; k < 5; ++k) acc[i][j][k] = 0.0;

  const double* ibase = in + ((size_t)(b * 109 + 2 * py) * 109 + 2 * px) * 8;

  for (int ky = 0; ky < 5; ++ky) {
    const double2* r0 = reinterpret_cast<const double2*>(ibase + (size_t)ky * 872);
    const double2* r1 = reinterpret_cast<const double2*>(ibase + (size_t)(ky + 1) * 872);
#pragma unroll
    for (int h = 0; h < 2; ++h) {  // input-channel halves 0..3 / 4..7
      double b0[24], b1[24];
#pragma unroll
      for (int j = 0; j < 6; ++j) {  // 6 window columns
        double2 u0 = r0[j * 4 + h * 2], u1 = r0[j * 4 + h * 2 + 1];
        b0[j * 4 + 0] = u0.x; b0[j * 4 + 1] = u0.y;
        b0[j * 4 + 2] = u1.x; b0[j * 4 + 3] = u1.y;
        double2 v0 = r1[j * 4 + h * 2], v1 = r1[j * 4 + h * 2 + 1];
        b1[j * 4 + 0] = v0.x; b1[j * 4 + 1] = v0.y;
        b1[j * 4 + 2] = v1.x; b1[j * 4 + 3] = v1.y;
      }
#pragma unroll
      for (int kx = 0; kx < 5; ++kx) {
#pragma unroll
        for (int cc = 0; cc < 4; ++cc) {
          int c = h * 4 + cc;
          double v00 = b0[kx * 4 + cc];
          double v01 = b0[(kx + 1) * 4 + cc];
          double v10 = b1[kx * 4 + cc];
          double v11 = b1[(kx + 1) * 4 + cc];
          const double* wp = &w64[((ky * 5 + kx) * 8 + c) * 10 + oh * 5];
#pragma unroll
          for (int oc = 0; oc < 5; ++oc) {
            double wv = wp[oc];  // uniform -> s_load
            acc[0][0][oc] = fma(v00, wv, acc[0][0][oc]);
            acc[0][1][oc] = fma(v01, wv, acc[0][1][oc]);
            acc[1][0][oc] = fma(v10, wv, acc[1][0][oc]);
            acc[1][1][oc] = fma(v11, wv, acc[1][1][oc]);
          }
        }
      }
    }
  }

  double* op = out + (size_t)idx * 10 + oh * 5;
#pragma unroll
  for (int oc = 0; oc < 5; ++oc) {
    double m = fmax(fmax(acc[0][0][oc], acc[0][1][oc]),
                    fmax(acc[1][0][oc], acc[1][1][oc]));
    op[oc] = fmax(m + b64[oh * 5 + oc], 0.0);
  }
}

// fc1 (27040->32) + ReLU, then fc2 (32->6). One block per batch, fp64.
__global__ __launch_bounds__(256) void k_fc(
    const double* __restrict__ xs, const float* __restrict__ w1,
    const float* __restrict__ b1, const float* __restrict__ w2,
    const float* __restrict__ b2, double* __restrict__ theta) {
  int b = blockIdx.x;
  int oc = threadIdx.x & 31;
  int chunk = threadIdx.x >> 5;  // 8 chunks of 3380
  const double* xrow = xs + (size_t)b * 27040;

  double s = 0.0;
  int i0 = chunk * 3380;
  for (int i = 0; i < 3380; ++i) {
    s = fma(xrow[i0 + i], (double)w1[(size_t)(i0 + i) * 32 + oc], s);
  }

  __shared__ double part[8][32];
  part[chunk][oc] = s;
  __syncthreads();

  __shared__ double h1[32];
  if (threadIdx.x < 32) {
    double v = (double)b1[threadIdx.x];
#pragma unroll
    for (int k = 0; k < 8; ++k) v += part[k][threadIdx.x];
    h1[threadIdx.x] = v > 0.0 ? v : 0.0;
  }
  __syncthreads();

  if (threadIdx.x < 6) {
    double v = (double)b2[threadIdx.x];
#pragma unroll
    for (int k = 0; k < 32; ++k) v += h1[k] * (double)w2[k * 6 + threadIdx.x];
    theta[b * 6 + threadIdx.x] = v;
  }
}

// affine grid + bilinear sampler, reference-exact (incl. extrapolation quirk).
__global__ __launch_bounds__(256) void k_sample(
    const float* __restrict__ img, const double* __restrict__ theta,
    float* __restrict__ out) {
  int idx = blockIdx.x * 256 + threadIdx.x;
  if (idx >= 64 * 224 * 224) return;
  int x = idx % 224;
  int t = idx / 224;
  int y = t % 224;
  int b = t / 224;

  const double* th = theta + b * 6;
  double t0 = th[0], t1 = th[1], t2 = th[2];
  double t3 = th[3], t4 = th[4], t5 = th[5];

  double xn = -1.0 + x * (2.0 / 223.0);
  double yn = -1.0 + y * (2.0 / 223.0);
  double xf = 0.5 * (t0 * xn + t1 * yn + t2 + 1.0) * 223.0;
  double yf = 0.5 * (t3 * xn + t4 * yn + t5 + 1.0) * 223.0;

  int x0 = (int)floor(xf);
  int y0 = (int)floor(yf);
  x0 = min(max(x0, 0), 223);
  y0 = min(max(y0, 0), 223);
  int x1 = min(x0 + 1, 223);
  int y1 = min(y0 + 1, 223);

  double x0f = (double)x0, x1f = (double)x1;
  double y0f = (double)y0, y1f = (double)y1;
  // weights from UNCLIPPED xf/yf — reference semantics (extrapolates)
  double wa = (x1f - xf) * (y1f - yf);
  double wb = (x1f - xf) * (yf - y0f);
  double wc = (xf - x0f) * (y1f - yf);
  double wd = (xf - x0f) * (yf - y0f);

  const float* p = img + (size_t)b * 224 * 224 * 3;
  const float* Ia = p + ((size_t)y0 * 224 + x0) * 3;
  const float* Ib = p + ((size_t)y1 * 224 + x0) * 3;
  const float* Ic = p + ((size_t)y0 * 224 + x1) * 3;
  const float* Id = p + ((size_t)y1 * 224 + x1) * 3;

  float* op = out + (size_t)idx * 3;
#pragma unroll
  for (int c = 0; c < 3; ++c) {
    op[c] = (float)(wa * (double)Ia[c] + wb * (double)Ib[c] +
                    wc * (double)Ic[c] + wd * (double)Id[c]);
  }
}

extern "C" void kernel_launch(void* const* d_in, const int* in_sizes, int n_in,
                              void* d_out, int out_size, void* d_ws, size_t ws_size,
                              hipStream_t stream) {
  const float* inputs  = (const float*)d_in[0];  // (64,224,224,3)
  const float* conv1_w = (const float*)d_in[1];  // (7,7,3,8)
  const float* conv1_b = (const float*)d_in[2];  // (8)
  const float* conv2_w = (const float*)d_in[3];  // (5,5,8,10)
  const float* conv2_b = (const float*)d_in[4];  // (10)
  const float* fc1_w   = (const float*)d_in[5];  // (27040,32)
  const float* fc1_b   = (const float*)d_in[6];  // (32)
  const float* fc2_w   = (const float*)d_in[7];  // (32,6)
  const float* fc2_b   = (const float*)d_in[8];  // (6)
  float* outp = (float*)d_out;                   // (64,224,224,3)

  // ws layout (8B aligned): theta | prepped f64 weights | pool1 | pool2
  double* theta = (double*)d_ws;                          // 64*6   = 3072 B
  double* wprep = (double*)((char*)d_ws + 3072);          // 3194*8 = 25552 B
  double* pool1 = (double*)((char*)d_ws + 28672);         // 6,081,152 f64
  double* pool2 = pool1 + 6081152;                        // 1,730,560 f64

  k_prep<<<13, 256, 0, stream>>>(conv1_w, conv1_b, conv2_w, conv2_b, wprep);

  {
    int total = 64 * 109 * 109;
    int blocks = (total + 255) / 256;
    k_conv1<<<blocks, 256, 0, stream>>>(inputs, wprep, pool1);
  }
  {
    int total = 64 * 52 * 52;
    int blocks = ((total + 255) / 256) * 2;  // x2: oc halves via blockIdx&1
    k_conv2<<<blocks, 256, 0, stream>>>(pool1, wprep, pool2);
  }
  k_fc<<<64, 256, 0, stream>>>(pool2, fc1_w, fc1_b, fc2_w, fc2_b, theta);
  {
    int total = 64 * 224 * 224;
    int blocks = (total + 255) / 256;
    k_sample<<<blocks, 256, 0, stream>>>(inputs, theta, outp);
  }
}

// Round 5
// 657.628 us; speedup vs baseline: 1.9969x; 1.9969x over previous
//
#include <hip/hip_runtime.h>

// ---------------------------------------------------------------------------
// STN pipeline, theta chain in FP64 (must match np float64 reference: sampler
// has floor() discontinuities at coord==223 with O(100..1000) jumps; f32
// noise upstream of theta flips floors -> fails. Any-order f64 lands ~1e-13
// from the np value -> flip set identical -> absmax stays ~73).
//
// R5: revert to R3's LDS-weight conv structure (R4's SGPR-weight experiment
// caused scratch spills: VGPR 32, FETCH 3.2 GB, 988 us). Fixes on top of R3:
//  - XCD batch-group swizzle (blockIdx&7 -> 8-batch group): per-XCD L2
//    working set ~6 MB instead of whole tensor (R3: FETCH 376 MB = 7.7x
//    input, every XCD fetched everything).
//  - conv2 oc-split x2 (wave-uniform) -> 1408 blocks, 5.3 waves/SIMD.
//  - fc: 4 independent partial sums to break the load-fma latency chain.
// ---------------------------------------------------------------------------

// conv1 + relu + maxpool : in (64,224,224,3) f32 -> out (64,109,109,8) f64
__global__ __launch_bounds__(256) void k_conv1(
    const float* __restrict__ in, const float* __restrict__ w,
    const float* __restrict__ bias, double* __restrict__ out) {
  __shared__ double sw[1176];  // (7,7,3,8) HWIO
  __shared__ double sb[8];
  for (int i = threadIdx.x; i < 1176; i += 256) sw[i] = (double)w[i];
  if (threadIdx.x < 8) sb[threadIdx.x] = (double)bias[threadIdx.x];
  __syncthreads();

  // XCD swizzle: group g handles batches 8g..8g+7. 47 blocks per batch.
  int g = blockIdx.x & 7;
  int i = blockIdx.x >> 3;          // 0..375
  int b_local = i / 47;
  int tile = i % 47;
  int b = g * 8 + b_local;
  int pix = tile * 256 + threadIdx.x;
  if (pix >= 109 * 109) return;
  int px = pix % 109;
  int py = pix / 109;

  double acc[2][2][8];
#pragma unroll
  for (int ii = 0; ii < 2; ++ii)
#pragma unroll
    for (int j = 0; j < 2; ++j)
#pragma unroll
      for (int k = 0; k < 8; ++k) acc[ii][j][k] = 0.0;

  const float* ibase = in + ((size_t)(b * 224 + 2 * py) * 224 + 2 * px) * 3;

  for (int ky = 0; ky < 7; ++ky) {
    const float2* r0 = reinterpret_cast<const float2*>(ibase + ky * 672);
    const float2* r1 = reinterpret_cast<const float2*>(ibase + (ky + 1) * 672);
    float a0[24], a1[24];
#pragma unroll
    for (int j = 0; j < 12; ++j) {
      float2 u = r0[j]; a0[2 * j] = u.x; a0[2 * j + 1] = u.y;
      float2 v = r1[j]; a1[2 * j] = v.x; a1[2 * j + 1] = v.y;
    }
#pragma unroll
    for (int kx = 0; kx < 7; ++kx) {
#pragma unroll
      for (int c = 0; c < 3; ++c) {
        double v00 = (double)a0[kx * 3 + c];
        double v01 = (double)a0[kx * 3 + 3 + c];
        double v10 = (double)a1[kx * 3 + c];
        double v11 = (double)a1[kx * 3 + 3 + c];
        const double* wp = &sw[((ky * 7 + kx) * 3 + c) * 8];
#pragma unroll
        for (int oc = 0; oc < 8; ++oc) {
          double wv = wp[oc];  // same addr across lanes -> LDS broadcast
          acc[0][0][oc] = fma(v00, wv, acc[0][0][oc]);
          acc[0][1][oc] = fma(v01, wv, acc[0][1][oc]);
          acc[1][0][oc] = fma(v10, wv, acc[1][0][oc]);
          acc[1][1][oc] = fma(v11, wv, acc[1][1][oc]);
        }
      }
    }
  }

  double* op = out + ((size_t)b * 11881 + pix) * 8;
#pragma unroll
  for (int oc = 0; oc < 8; ++oc) {
    double m = fmax(fmax(acc[0][0][oc], acc[0][1][oc]),
                    fmax(acc[1][0][oc], acc[1][1][oc]));
    op[oc] = fmax(m + sb[oc], 0.0);
  }
}

// conv2 + relu + maxpool : in (64,109,109,8) f64 -> out (64,52,52,10) f64
// oc halves via wave-uniform index bit; XCD batch-group swizzle.
__global__ __launch_bounds__(256) void k_conv2(
    const double* __restrict__ in, const float* __restrict__ w,
    const float* __restrict__ bias, double* __restrict__ out) {
  __shared__ double sw[2000];  // (5,5,8,10) HWIO
  __shared__ double sb[10];
  for (int i = threadIdx.x; i < 2000; i += 256) sw[i] = (double)w[i];
  if (threadIdx.x < 10) sb[threadIdx.x] = (double)bias[threadIdx.x];
  __syncthreads();

  // group g (blk&7) -> batches 8g..8g+7; within: oh(1b), b_local(/11), tile
  int g = blockIdx.x & 7;
  int i = blockIdx.x >> 3;          // 0..175
  int oh = i & 1;                   // oc half: 0..4 / 5..9
  int j = i >> 1;                   // 0..87
  int b_local = j / 11;
  int tile = j % 11;
  int b = g * 8 + b_local;
  int pix = tile * 256 + threadIdx.x;
  if (pix >= 52 * 52) return;
  int px = pix % 52;
  int py = pix / 52;

  double acc[2][2][5];
#pragma unroll
  for (int ii = 0; ii < 2; ++ii)
#pragma unroll
    for (int jj = 0; jj < 2; ++jj)
#pragma unroll
      for (int k = 0; k < 5; ++k) acc[ii][jj][k] = 0.0;

  const double* ibase = in + ((size_t)(b * 109 + 2 * py) * 109 + 2 * px) * 8;

  for (int ky = 0; ky < 5; ++ky) {
    const double2* r0 = reinterpret_cast<const double2*>(ibase + (size_t)ky * 872);
    const double2* r1 = reinterpret_cast<const double2*>(ibase + (size_t)(ky + 1) * 872);
#pragma unroll
    for (int h = 0; h < 2; ++h) {  // input-channel halves 0..3 / 4..7
      double b0[24], b1[24];
#pragma unroll
      for (int jc = 0; jc < 6; ++jc) {  // 6 window columns
        double2 u0 = r0[jc * 4 + h * 2], u1 = r0[jc * 4 + h * 2 + 1];
        b0[jc * 4 + 0] = u0.x; b0[jc * 4 + 1] = u0.y;
        b0[jc * 4 + 2] = u1.x; b0[jc * 4 + 3] = u1.y;
        double2 v0 = r1[jc * 4 + h * 2], v1 = r1[jc * 4 + h * 2 + 1];
        b1[jc * 4 + 0] = v0.x; b1[jc * 4 + 1] = v0.y;
        b1[jc * 4 + 2] = v1.x; b1[jc * 4 + 3] = v1.y;
      }
#pragma unroll
      for (int kx = 0; kx < 5; ++kx) {
#pragma unroll
        for (int cc = 0; cc < 4; ++cc) {
          int c = h * 4 + cc;
          double v00 = b0[kx * 4 + cc];
          double v01 = b0[(kx + 1) * 4 + cc];
          double v10 = b1[kx * 4 + cc];
          double v11 = b1[(kx + 1) * 4 + cc];
          const double* wp = &sw[((ky * 5 + kx) * 8 + c) * 10 + oh * 5];
#pragma unroll
          for (int oc = 0; oc < 5; ++oc) {
            double wv = wp[oc];  // uniform addr -> broadcast
            acc[0][0][oc] = fma(v00, wv, acc[0][0][oc]);
            acc[0][1][oc] = fma(v01, wv, acc[0][1][oc]);
            acc[1][0][oc] = fma(v10, wv, acc[1][0][oc]);
            acc[1][1][oc] = fma(v11, wv, acc[1][1][oc]);
          }
        }
      }
    }
  }

  double* op = out + ((size_t)b * 2704 + pix) * 10 + oh * 5;
#pragma unroll
  for (int oc = 0; oc < 5; ++oc) {
    double m = fmax(fmax(acc[0][0][oc], acc[0][1][oc]),
                    fmax(acc[1][0][oc], acc[1][1][oc]));
    op[oc] = fmax(m + sb[oh * 5 + oc], 0.0);
  }
}

// fc1 (27040->32) + ReLU, then fc2 (32->6). One block per batch, fp64.
// 4 independent partial sums break the serial load->fma chain.
__global__ __launch_bounds__(256) void k_fc(
    const double* __restrict__ xs, const float* __restrict__ w1,
    const float* __restrict__ b1, const float* __restrict__ w2,
    const float* __restrict__ b2, double* __restrict__ theta) {
  int b = blockIdx.x;
  int oc = threadIdx.x & 31;
  int chunk = threadIdx.x >> 5;  // 8 chunks of 3380
  const double* xrow = xs + (size_t)b * 27040;

  double s0 = 0.0, s1 = 0.0, s2 = 0.0, s3 = 0.0;
  int i0 = chunk * 3380;
  for (int i = 0; i < 3380; i += 4) {
    s0 = fma(xrow[i0 + i],     (double)w1[(size_t)(i0 + i) * 32 + oc],     s0);
    s1 = fma(xrow[i0 + i + 1], (double)w1[(size_t)(i0 + i + 1) * 32 + oc], s1);
    s2 = fma(xrow[i0 + i + 2], (double)w1[(size_t)(i0 + i + 2) * 32 + oc], s2);
    s3 = fma(xrow[i0 + i + 3], (double)w1[(size_t)(i0 + i + 3) * 32 + oc], s3);
  }
  double s = (s0 + s1) + (s2 + s3);

  __shared__ double part[8][32];
  part[chunk][oc] = s;
  __syncthreads();

  __shared__ double h1[32];
  if (threadIdx.x < 32) {
    double v = (double)b1[threadIdx.x];
#pragma unroll
    for (int k = 0; k < 8; ++k) v += part[k][threadIdx.x];
    h1[threadIdx.x] = v > 0.0 ? v : 0.0;
  }
  __syncthreads();

  if (threadIdx.x < 6) {
    double v = (double)b2[threadIdx.x];
#pragma unroll
    for (int k = 0; k < 32; ++k) v += h1[k] * (double)w2[k * 6 + threadIdx.x];
    theta[b * 6 + threadIdx.x] = v;
  }
}

// affine grid + bilinear sampler, reference-exact (incl. extrapolation quirk).
__global__ __launch_bounds__(256) void k_sample(
    const float* __restrict__ img, const double* __restrict__ theta,
    float* __restrict__ out) {
  int idx = blockIdx.x * 256 + threadIdx.x;
  if (idx >= 64 * 224 * 224) return;
  int x = idx % 224;
  int t = idx / 224;
  int y = t % 224;
  int b = t / 224;

  const double* th = theta + b * 6;
  double t0 = th[0], t1 = th[1], t2 = th[2];
  double t3 = th[3], t4 = th[4], t5 = th[5];

  double xn = -1.0 + x * (2.0 / 223.0);
  double yn = -1.0 + y * (2.0 / 223.0);
  double xf = 0.5 * (t0 * xn + t1 * yn + t2 + 1.0) * 223.0;
  double yf = 0.5 * (t3 * xn + t4 * yn + t5 + 1.0) * 223.0;

  int x0 = (int)floor(xf);
  int y0 = (int)floor(yf);
  x0 = min(max(x0, 0), 223);
  y0 = min(max(y0, 0), 223);
  int x1 = min(x0 + 1, 223);
  int y1 = min(y0 + 1, 223);

  double x0f = (double)x0, x1f = (double)x1;
  double y0f = (double)y0, y1f = (double)y1;
  // weights from UNCLIPPED xf/yf — reference semantics (extrapolates)
  double wa = (x1f - xf) * (y1f - yf);
  double wb = (x1f - xf) * (yf - y0f);
  double wc = (xf - x0f) * (y1f - yf);
  double wd = (xf - x0f) * (yf - y0f);

  const float* p = img + (size_t)b * 224 * 224 * 3;
  const float* Ia = p + ((size_t)y0 * 224 + x0) * 3;
  const float* Ib = p + ((size_t)y1 * 224 + x0) * 3;
  const float* Ic = p + ((size_t)y0 * 224 + x1) * 3;
  const float* Id = p + ((size_t)y1 * 224 + x1) * 3;

  float* op = out + (size_t)idx * 3;
#pragma unroll
  for (int c = 0; c < 3; ++c) {
    op[c] = (float)(wa * (double)Ia[c] + wb * (double)Ib[c] +
                    wc * (double)Ic[c] + wd * (double)Id[c]);
  }
}

extern "C" void kernel_launch(void* const* d_in, const int* in_sizes, int n_in,
                              void* d_out, int out_size, void* d_ws, size_t ws_size,
                              hipStream_t stream) {
  const float* inputs  = (const float*)d_in[0];  // (64,224,224,3)
  const float* conv1_w = (const float*)d_in[1];  // (7,7,3,8)
  const float* conv1_b = (const float*)d_in[2];  // (8)
  const float* conv2_w = (const float*)d_in[3];  // (5,5,8,10)
  const float* conv2_b = (const float*)d_in[4];  // (10)
  const float* fc1_w   = (const float*)d_in[5];  // (27040,32)
  const float* fc1_b   = (const float*)d_in[6];  // (32)
  const float* fc2_w   = (const float*)d_in[7];  // (32,6)
  const float* fc2_b   = (const float*)d_in[8];  // (6)
  float* outp = (float*)d_out;                   // (64,224,224,3)

  // ws layout (8B aligned): theta | pool1 f64 | pool2 f64
  double* theta = (double*)d_ws;                    // 64*6
  double* pool1 = (double*)((char*)d_ws + 4096);    // 64*109*109*8 = 6,081,152
  double* pool2 = pool1 + 6081152;                  // 64*52*52*10  = 1,730,560

  // Stage 1: 47 blocks/batch * 64 batches, XCD-grouped
  k_conv1<<<47 * 64, 256, 0, stream>>>(inputs, conv1_w, conv1_b, pool1);
  // Stage 2: 11 blocks/batch * 2 oc-halves * 64 batches, XCD-grouped
  k_conv2<<<11 * 2 * 64, 256, 0, stream>>>(pool1, conv2_w, conv2_b, pool2);
  // Stage 3
  k_fc<<<64, 256, 0, stream>>>(pool2, fc1_w, fc1_b, fc2_w, fc2_b, theta);
  // Stage 4
  {
    int total = 64 * 224 * 224;
    int blocks = (total + 255) / 256;
    k_sample<<<blocks, 256, 0, stream>>>(inputs, theta, outp);
  }
}

// Round 6
// 655.528 us; speedup vs baseline: 2.0033x; 1.0032x over previous
//
#include <hip/hip_runtime.h>

// ---------------------------------------------------------------------------
// STN pipeline, theta chain in FP64 (must match np float64 reference: sampler
// has floor() discontinuities at coord==223 with O(100..1000) jumps; f32
// noise upstream of theta flips floors -> fails. Any-order f64 lands ~1e-13
// from the np value -> flip set identical -> absmax stays ~73).
//
// R6: ONE change vs R5 — __launch_bounds__(256, 2) on both convs.
// R5 counters showed conv2 at VGPR_Count=52 while the kernel needs ~150
// (acc 40 + window 96 + addr): the occupancy heuristic spilled the window
// arrays to scratch, making the kernel latency-bound (VALUBusy 14.4%,
// dur 273us vs 36us f64-FMA floor). min-waves=2 -> 256-VGPR budget,
// no spills. Keep XCD batch-group swizzle (FETCH 376->25 MB, keep it).
// ---------------------------------------------------------------------------

// conv1 + relu + maxpool : in (64,224,224,3) f32 -> out (64,109,109,8) f64
__global__ __launch_bounds__(256, 2) void k_conv1(
    const float* __restrict__ in, const float* __restrict__ w,
    const float* __restrict__ bias, double* __restrict__ out) {
  __shared__ double sw[1176];  // (7,7,3,8) HWIO
  __shared__ double sb[8];
  for (int i = threadIdx.x; i < 1176; i += 256) sw[i] = (double)w[i];
  if (threadIdx.x < 8) sb[threadIdx.x] = (double)bias[threadIdx.x];
  __syncthreads();

  // XCD swizzle: group g handles batches 8g..8g+7. 47 blocks per batch.
  int g = blockIdx.x & 7;
  int i = blockIdx.x >> 3;          // 0..375
  int b_local = i / 47;
  int tile = i % 47;
  int b = g * 8 + b_local;
  int pix = tile * 256 + threadIdx.x;
  if (pix >= 109 * 109) return;
  int px = pix % 109;
  int py = pix / 109;

  double acc[2][2][8];
#pragma unroll
  for (int ii = 0; ii < 2; ++ii)
#pragma unroll
    for (int j = 0; j < 2; ++j)
#pragma unroll
      for (int k = 0; k < 8; ++k) acc[ii][j][k] = 0.0;

  const float* ibase = in + ((size_t)(b * 224 + 2 * py) * 224 + 2 * px) * 3;

  for (int ky = 0; ky < 7; ++ky) {
    const float2* r0 = reinterpret_cast<const float2*>(ibase + ky * 672);
    const float2* r1 = reinterpret_cast<const float2*>(ibase + (ky + 1) * 672);
    float a0[24], a1[24];
#pragma unroll
    for (int j = 0; j < 12; ++j) {
      float2 u = r0[j]; a0[2 * j] = u.x; a0[2 * j + 1] = u.y;
      float2 v = r1[j]; a1[2 * j] = v.x; a1[2 * j + 1] = v.y;
    }
#pragma unroll
    for (int kx = 0; kx < 7; ++kx) {
#pragma unroll
      for (int c = 0; c < 3; ++c) {
        double v00 = (double)a0[kx * 3 + c];
        double v01 = (double)a0[kx * 3 + 3 + c];
        double v10 = (double)a1[kx * 3 + c];
        double v11 = (double)a1[kx * 3 + 3 + c];
        const double* wp = &sw[((ky * 7 + kx) * 3 + c) * 8];
#pragma unroll
        for (int oc = 0; oc < 8; ++oc) {
          double wv = wp[oc];  // same addr across lanes -> LDS broadcast
          acc[0][0][oc] = fma(v00, wv, acc[0][0][oc]);
          acc[0][1][oc] = fma(v01, wv, acc[0][1][oc]);
          acc[1][0][oc] = fma(v10, wv, acc[1][0][oc]);
          acc[1][1][oc] = fma(v11, wv, acc[1][1][oc]);
        }
      }
    }
  }

  double* op = out + ((size_t)b * 11881 + pix) * 8;
#pragma unroll
  for (int oc = 0; oc < 8; ++oc) {
    double m = fmax(fmax(acc[0][0][oc], acc[0][1][oc]),
                    fmax(acc[1][0][oc], acc[1][1][oc]));
    op[oc] = fmax(m + sb[oc], 0.0);
  }
}

// conv2 + relu + maxpool : in (64,109,109,8) f64 -> out (64,52,52,10) f64
// oc halves via wave-uniform index bit; XCD batch-group swizzle.
__global__ __launch_bounds__(256, 2) void k_conv2(
    const double* __restrict__ in, const float* __restrict__ w,
    const float* __restrict__ bias, double* __restrict__ out) {
  __shared__ double sw[2000];  // (5,5,8,10) HWIO
  __shared__ double sb[10];
  for (int i = threadIdx.x; i < 2000; i += 256) sw[i] = (double)w[i];
  if (threadIdx.x < 10) sb[threadIdx.x] = (double)bias[threadIdx.x];
  __syncthreads();

  // group g (blk&7) -> batches 8g..8g+7; within: oh(1b), b_local(/11), tile
  int g = blockIdx.x & 7;
  int i = blockIdx.x >> 3;          // 0..175
  int oh = i & 1;                   // oc half: 0..4 / 5..9
  int j = i >> 1;                   // 0..87
  int b_local = j / 11;
  int tile = j % 11;
  int b = g * 8 + b_local;
  int pix = tile * 256 + threadIdx.x;
  if (pix >= 52 * 52) return;
  int px = pix % 52;
  int py = pix / 52;

  double acc[2][2][5];
#pragma unroll
  for (int ii = 0; ii < 2; ++ii)
#pragma unroll
    for (int jj = 0; jj < 2; ++jj)
#pragma unroll
      for (int k = 0; k < 5; ++k) acc[ii][jj][k] = 0.0;

  const double* ibase = in + ((size_t)(b * 109 + 2 * py) * 109 + 2 * px) * 8;

  for (int ky = 0; ky < 5; ++ky) {
    const double2* r0 = reinterpret_cast<const double2*>(ibase + (size_t)ky * 872);
    const double2* r1 = reinterpret_cast<const double2*>(ibase + (size_t)(ky + 1) * 872);
#pragma unroll
    for (int h = 0; h < 2; ++h) {  // input-channel halves 0..3 / 4..7
      double b0[24], b1[24];
#pragma unroll
      for (int jc = 0; jc < 6; ++jc) {  // 6 window columns
        double2 u0 = r0[jc * 4 + h * 2], u1 = r0[jc * 4 + h * 2 + 1];
        b0[jc * 4 + 0] = u0.x; b0[jc * 4 + 1] = u0.y;
        b0[jc * 4 + 2] = u1.x; b0[jc * 4 + 3] = u1.y;
        double2 v0 = r1[jc * 4 + h * 2], v1 = r1[jc * 4 + h * 2 + 1];
        b1[jc * 4 + 0] = v0.x; b1[jc * 4 + 1] = v0.y;
        b1[jc * 4 + 2] = v1.x; b1[jc * 4 + 3] = v1.y;
      }
#pragma unroll
      for (int kx = 0; kx < 5; ++kx) {
#pragma unroll
        for (int cc = 0; cc < 4; ++cc) {
          int c = h * 4 + cc;
          double v00 = b0[kx * 4 + cc];
          double v01 = b0[(kx + 1) * 4 + cc];
          double v10 = b1[kx * 4 + cc];
          double v11 = b1[(kx + 1) * 4 + cc];
          const double* wp = &sw[((ky * 5 + kx) * 8 + c) * 10 + oh * 5];
#pragma unroll
          for (int oc = 0; oc < 5; ++oc) {
            double wv = wp[oc];  // uniform addr -> broadcast
            acc[0][0][oc] = fma(v00, wv, acc[0][0][oc]);
            acc[0][1][oc] = fma(v01, wv, acc[0][1][oc]);
            acc[1][0][oc] = fma(v10, wv, acc[1][0][oc]);
            acc[1][1][oc] = fma(v11, wv, acc[1][1][oc]);
          }
        }
      }
    }
  }

  double* op = out + ((size_t)b * 2704 + pix) * 10 + oh * 5;
#pragma unroll
  for (int oc = 0; oc < 5; ++oc) {
    double m = fmax(fmax(acc[0][0][oc], acc[0][1][oc]),
                    fmax(acc[1][0][oc], acc[1][1][oc]));
    op[oc] = fmax(m + sb[oh * 5 + oc], 0.0);
  }
}

// fc1 (27040->32) + ReLU, then fc2 (32->6). One block per batch, fp64.
__global__ __launch_bounds__(256) void k_fc(
    const double* __restrict__ xs, const float* __restrict__ w1,
    const float* __restrict__ b1, const float* __restrict__ w2,
    const float* __restrict__ b2, double* __restrict__ theta) {
  int b = blockIdx.x;
  int oc = threadIdx.x & 31;
  int chunk = threadIdx.x >> 5;  // 8 chunks of 3380
  const double* xrow = xs + (size_t)b * 27040;

  double s0 = 0.0, s1 = 0.0, s2 = 0.0, s3 = 0.0;
  int i0 = chunk * 3380;
  for (int i = 0; i < 3380; i += 4) {
    s0 = fma(xrow[i0 + i],     (double)w1[(size_t)(i0 + i) * 32 + oc],     s0);
    s1 = fma(xrow[i0 + i + 1], (double)w1[(size_t)(i0 + i + 1) * 32 + oc], s1);
    s2 = fma(xrow[i0 + i + 2], (double)w1[(size_t)(i0 + i + 2) * 32 + oc], s2);
    s3 = fma(xrow[i0 + i + 3], (double)w1[(size_t)(i0 + i + 3) * 32 + oc], s3);
  }
  double s = (s0 + s1) + (s2 + s3);

  __shared__ double part[8][32];
  part[chunk][oc] = s;
  __syncthreads();

  __shared__ double h1[32];
  if (threadIdx.x < 32) {
    double v = (double)b1[threadIdx.x];
#pragma unroll
    for (int k = 0; k < 8; ++k) v += part[k][threadIdx.x];
    h1[threadIdx.x] = v > 0.0 ? v : 0.0;
  }
  __syncthreads();

  if (threadIdx.x < 6) {
    double v = (double)b2[threadIdx.x];
#pragma unroll
    for (int k = 0; k < 32; ++k) v += h1[k] * (double)w2[k * 6 + threadIdx.x];
    theta[b * 6 + threadIdx.x] = v;
  }
}

// affine grid + bilinear sampler, reference-exact (incl. extrapolation quirk).
__global__ __launch_bounds__(256) void k_sample(
    const float* __restrict__ img, const double* __restrict__ theta,
    float* __restrict__ out) {
  int idx = blockIdx.x * 256 + threadIdx.x;
  if (idx >= 64 * 224 * 224) return;
  int x = idx % 224;
  int t = idx / 224;
  int y = t % 224;
  int b = t / 224;

  const double* th = theta + b * 6;
  double t0 = th[0], t1 = th[1], t2 = th[2];
  double t3 = th[3], t4 = th[4], t5 = th[5];

  double xn = -1.0 + x * (2.0 / 223.0);
  double yn = -1.0 + y * (2.0 / 223.0);
  double xf = 0.5 * (t0 * xn + t1 * yn + t2 + 1.0) * 223.0;
  double yf = 0.5 * (t3 * xn + t4 * yn + t5 + 1.0) * 223.0;

  int x0 = (int)floor(xf);
  int y0 = (int)floor(yf);
  x0 = min(max(x0, 0), 223);
  y0 = min(max(y0, 0), 223);
  int x1 = min(x0 + 1, 223);
  int y1 = min(y0 + 1, 223);

  double x0f = (double)x0, x1f = (double)x1;
  double y0f = (double)y0, y1f = (double)y1;
  // weights from UNCLIPPED xf/yf — reference semantics (extrapolates)
  double wa = (x1f - xf) * (y1f - yf);
  double wb = (x1f - xf) * (yf - y0f);
  double wc = (xf - x0f) * (y1f - yf);
  double wd = (xf - x0f) * (yf - y0f);

  const float* p = img + (size_t)b * 224 * 224 * 3;
  const float* Ia = p + ((size_t)y0 * 224 + x0) * 3;
  const float* Ib = p + ((size_t)y1 * 224 + x0) * 3;
  const float* Ic = p + ((size_t)y0 * 224 + x1) * 3;
  const float* Id = p + ((size_t)y1 * 224 + x1) * 3;

  float* op = out + (size_t)idx * 3;
#pragma unroll
  for (int c = 0; c < 3; ++c) {
    op[c] = (float)(wa * (double)Ia[c] + wb * (double)Ib[c] +
                    wc * (double)Ic[c] + wd * (double)Id[c]);
  }
}

extern "C" void kernel_launch(void* const* d_in, const int* in_sizes, int n_in,
                              void* d_out, int out_size, void* d_ws, size_t ws_size,
                              hipStream_t stream) {
  const float* inputs  = (const float*)d_in[0];  // (64,224,224,3)
  const float* conv1_w = (const float*)d_in[1];  // (7,7,3,8)
  const float* conv1_b = (const float*)d_in[2];  // (8)
  const float* conv2_w = (const float*)d_in[3];  // (5,5,8,10)
  const float* conv2_b = (const float*)d_in[4];  // (10)
  const float* fc1_w   = (const float*)d_in[5];  // (27040,32)
  const float* fc1_b   = (const float*)d_in[6];  // (32)
  const float* fc2_w   = (const float*)d_in[7];  // (32,6)
  const float* fc2_b   = (const float*)d_in[8];  // (6)
  float* outp = (float*)d_out;                   // (64,224,224,3)

  // ws layout (8B aligned): theta | pool1 f64 | pool2 f64
  double* theta = (double*)d_ws;                    // 64*6
  double* pool1 = (double*)((char*)d_ws + 4096);    // 64*109*109*8 = 6,081,152
  double* pool2 = pool1 + 6081152;                  // 64*52*52*10  = 1,730,560

  // Stage 1: 47 blocks/batch * 64 batches, XCD-grouped
  k_conv1<<<47 * 64, 256, 0, stream>>>(inputs, conv1_w, conv1_b, pool1);
  // Stage 2: 11 blocks/batch * 2 oc-halves * 64 batches, XCD-grouped
  k_conv2<<<11 * 2 * 64, 256, 0, stream>>>(pool1, conv2_w, conv2_b, pool2);
  // Stage 3
  k_fc<<<64, 256, 0, stream>>>(pool2, fc1_w, fc1_b, fc2_w, fc2_b, theta);
  // Stage 4
  {
    int total = 64 * 224 * 224;
    int blocks = (total + 255) / 256;
    k_sample<<<blocks, 256, 0, stream>>>(inputs, theta, outp);
  }
}

// Round 7
// 476.492 us; speedup vs baseline: 2.7560x; 1.3757x over previous
//
#include <hip/hip_runtime.h>

// ---------------------------------------------------------------------------
// STN pipeline, theta chain in FP64 (must match np float64 reference: sampler
// has floor() discontinuities at coord==223 with O(100..1000) jumps; f32
// noise upstream of theta flips floors -> fails. Any-order f64 lands ~1e-13
// from the np value -> flip set identical -> absmax stays ~73).
//
// R7: structural fix for the latency-bound convs. R6 proved the allocator
// pins VGPR=52 (40 of them = f64 acc) leaving no registers for in-flight
// loads -> near-serial load->wait->use schedule (VALUBusy 14.9%). New
// structure: ALL inner-loop operands from LDS, staged cooperatively with
// bulk coalesced loads (no dependent consumer before the barrier ->
// latency-immune). Weights packed 16B-aligned. fc split 64->512 blocks.
// ---------------------------------------------------------------------------

// conv1 + relu + maxpool : in (64,224,224,3) f32 -> out (64,109,109,8) f64
// Block: one batch, 2 pooled rows x full width (218 pixels). LDS: input
// row-band 10x224x3 f32 (26.9 KB) + weights 147x8 f64 (9.4 KB).
__global__ __launch_bounds__(256) void k_conv1(
    const float* __restrict__ in, const float* __restrict__ w,
    const float* __restrict__ bias, double* __restrict__ out) {
  __shared__ float win[10 * 672];   // [row][col*3+ch]
  __shared__ double sw[147 * 8];    // [tap(ky,kx,c)][oc] — same layout as HWIO
  __shared__ double sb[8];
  for (int i = threadIdx.x; i < 1176; i += 256) sw[i] = (double)w[i];
  if (threadIdx.x < 8) sb[threadIdx.x] = (double)bias[threadIdx.x];

  // XCD swizzle: g = batch group. 55 tiles of 2 pooled rows per batch.
  int g = blockIdx.x & 7;
  int i = blockIdx.x >> 3;          // 0..439
  int b = g * 8 + i / 55;
  int tile = i % 55;
  int r0 = 4 * tile;                // first input row of the band

  // stage 10 input rows (clamped at 223), full width, as float4
  const float* ib = in + (size_t)b * 224 * 672 / 3 * 3;  // b*224*224*3
  {
    const float* ibb = in + (size_t)b * 150528;
    for (int idx = threadIdx.x; idx < 10 * 168; idx += 256) {
      int rr = idx / 168, c4 = idx % 168;
      int row = min(r0 + rr, 223);
      float4 v = reinterpret_cast<const float4*>(ibb + (size_t)row * 672)[c4];
      reinterpret_cast<float4*>(&win[rr * 672])[c4] = v;
    }
  }
  __syncthreads();

  int pix = threadIdx.x;            // 0..217 active
  if (pix < 218) {
    int px = pix % 109;
    int pyl = pix / 109;            // 0 or 1
    int py = 2 * tile + pyl;
    if (py < 109) {                 // last tile has 1 valid row
      double acc[2][2][8];
#pragma unroll
      for (int ii = 0; ii < 2; ++ii)
#pragma unroll
        for (int j = 0; j < 2; ++j)
#pragma unroll
          for (int k = 0; k < 8; ++k) acc[ii][j][k] = 0.0;

      for (int ky = 0; ky < 7; ++ky) {
        const float* r0p = &win[(2 * pyl + ky) * 672 + 6 * px];
        const float* r1p = r0p + 672;
        float a0[24], a1[24];
#pragma unroll
        for (int j = 0; j < 12; ++j) {
          float2 u = reinterpret_cast<const float2*>(r0p)[j];
          a0[2 * j] = u.x; a0[2 * j + 1] = u.y;
          float2 v = reinterpret_cast<const float2*>(r1p)[j];
          a1[2 * j] = v.x; a1[2 * j + 1] = v.y;
        }
#pragma unroll
        for (int kx = 0; kx < 7; ++kx) {
#pragma unroll
          for (int c = 0; c < 3; ++c) {
            double v00 = (double)a0[kx * 3 + c];
            double v01 = (double)a0[kx * 3 + 3 + c];
            double v10 = (double)a1[kx * 3 + c];
            double v11 = (double)a1[kx * 3 + 3 + c];
            const double* wp = &sw[((ky * 7 + kx) * 3 + c) * 8];
#pragma unroll
            for (int oc = 0; oc < 8; ++oc) {
              double wv = wp[oc];
              acc[0][0][oc] = fma(v00, wv, acc[0][0][oc]);
              acc[0][1][oc] = fma(v01, wv, acc[0][1][oc]);
              acc[1][0][oc] = fma(v10, wv, acc[1][0][oc]);
              acc[1][1][oc] = fma(v11, wv, acc[1][1][oc]);
            }
          }
        }
      }

      double* op = out + ((size_t)b * 11881 + (size_t)py * 109 + px) * 8;
#pragma unroll
      for (int oc = 0; oc < 8; ++oc) {
        double m = fmax(fmax(acc[0][0][oc], acc[0][1][oc]),
                        fmax(acc[1][0][oc], acc[1][1][oc]));
        op[oc] = fmax(m + sb[oc], 0.0);
      }
    }
  }
}

// conv2 + relu + maxpool : in (64,109,109,8) f64 -> out (64,52,52,10) f64
// Block: one batch, 2 pooled rows x full width; 208 threads = 104 pixels x
// 2 oc-halves. Two channel-half passes, each staging 8x109x4 f64 (27.9 KB).
// Weights [tap][12] padded: slot = oh*6+oc -> 16B-aligned 5-double rows.
__global__ __launch_bounds__(256) void k_conv2(
    const double* __restrict__ in, const float* __restrict__ w,
    const float* __restrict__ bias, double* __restrict__ out) {
  __shared__ double win[8 * 109 * 4];  // [rr][x][cc]
  __shared__ double sw[200 * 12];      // [tap(ky,kx,c)][oh*6+oc]
  __shared__ double sb[10];
  for (int i = threadIdx.x; i < 2000; i += 256) {
    int tap = i / 10, oc = i % 10;
    sw[tap * 12 + (oc / 5) * 6 + (oc % 5)] = (double)w[i];
  }
  if (threadIdx.x < 10) sb[threadIdx.x] = (double)bias[threadIdx.x];

  // XCD swizzle; 26 tiles of 2 pooled rows per batch.
  int g = blockIdx.x & 7;
  int i = blockIdx.x >> 3;          // 0..207
  int b = g * 8 + i / 26;
  int tile = i % 26;
  int r0 = 4 * tile;                // first conv2-input row (max 100+7=107<=108)

  int px = threadIdx.x % 52;
  int pyl = (threadIdx.x / 52) & 1;
  int oh = threadIdx.x / 104;       // 0,1 (threads 208..255 idle in compute)

  double acc[2][2][5];
#pragma unroll
  for (int ii = 0; ii < 2; ++ii)
#pragma unroll
    for (int jj = 0; jj < 2; ++jj)
#pragma unroll
      for (int k = 0; k < 5; ++k) acc[ii][jj][k] = 0.0;

  const double* ib = in + (size_t)b * 11881 * 8;

  for (int h = 0; h < 2; ++h) {
    __syncthreads();  // also covers weight staging before first use
    // stage 8 rows x 109 cols x channels [h*4 .. h*4+3] as double2
    for (int idx = threadIdx.x; idx < 1744; idx += 256) {
      int d2 = idx & 1;
      int x = (idx >> 1) % 109;
      int rr = (idx >> 1) / 109;
      double2 v = *reinterpret_cast<const double2*>(
          ib + ((size_t)(r0 + rr) * 109 + x) * 8 + h * 4 + d2 * 2);
      *reinterpret_cast<double2*>(&win[((size_t)rr * 109 + x) * 4 + d2 * 2]) = v;
    }
    __syncthreads();

    if (threadIdx.x < 208) {
#pragma unroll
      for (int ky = 0; ky < 5; ++ky) {
        int rr0 = 2 * pyl + ky;
#pragma unroll
        for (int kx = 0; kx < 5; ++kx) {
          const double* p00 = &win[((size_t)rr0 * 109 + 2 * px + kx) * 4];
          const double* p01 = p00 + 4;
          const double* p10 = p00 + 109 * 4;
          const double* p11 = p10 + 4;
#pragma unroll
          for (int cc = 0; cc < 4; ++cc) {
            int c = h * 4 + cc;
            double v00 = p00[cc], v01 = p01[cc];
            double v10 = p10[cc], v11 = p11[cc];
            const double* wp = &sw[((ky * 5 + kx) * 8 + c) * 12 + oh * 6];
#pragma unroll
            for (int oc = 0; oc < 5; ++oc) {
              double wv = wp[oc];
              acc[0][0][oc] = fma(v00, wv, acc[0][0][oc]);
              acc[0][1][oc] = fma(v01, wv, acc[0][1][oc]);
              acc[1][0][oc] = fma(v10, wv, acc[1][0][oc]);
              acc[1][1][oc] = fma(v11, wv, acc[1][1][oc]);
            }
          }
        }
      }
    }
  }

  if (threadIdx.x < 208) {
    int py = 2 * tile + pyl;  // < 52 always
    double* op = out + ((size_t)b * 2704 + (size_t)py * 52 + px) * 10 + oh * 5;
#pragma unroll
    for (int oc = 0; oc < 5; ++oc) {
      double m = fmax(fmax(acc[0][0][oc], acc[0][1][oc]),
                      fmax(acc[1][0][oc], acc[1][1][oc]));
      op[oc] = fmax(m + sb[oh * 5 + oc], 0.0);
    }
  }
}

// fc1 partial dots: grid 512 = (64 b) x (8 q); block 256 = 32 oc x 8 strips.
// part[(b*8+q)*32+oc] = sum over q's 3392-chunk.
__global__ __launch_bounds__(256) void k_fc1(
    const double* __restrict__ xs, const float* __restrict__ w1,
    double* __restrict__ part) {
  int b = blockIdx.x >> 3;
  int q = blockIdx.x & 7;
  int oc = threadIdx.x & 31;
  int s = threadIdx.x >> 5;
  const double* xrow = xs + (size_t)b * 27040;

  int i0 = q * 3392 + s * 424;
  int i1 = min(i0 + 424, 27040);
  double s0 = 0.0, s1 = 0.0;
  for (int i = i0; i + 1 < i1; i += 2) {
    s0 = fma(xrow[i],     (double)w1[(size_t)i * 32 + oc],       s0);
    s1 = fma(xrow[i + 1], (double)w1[(size_t)(i + 1) * 32 + oc], s1);
  }
  if (((i1 - i0) & 1) && i0 < i1)
    s0 = fma(xrow[i1 - 1], (double)w1[(size_t)(i1 - 1) * 32 + oc], s0);

  __shared__ double red[8][32];
  red[s][oc] = s0 + s1;
  __syncthreads();
  if (threadIdx.x < 32) {
    double v = 0.0;
#pragma unroll
    for (int k = 0; k < 8; ++k) v += red[k][threadIdx.x];
    part[((size_t)b * 8 + q) * 32 + threadIdx.x] = v;
  }
}

// fc1 reduce + ReLU + fc2 -> theta. 64 blocks x 64 threads.
__global__ __launch_bounds__(64) void k_fc2(
    const double* __restrict__ part, const float* __restrict__ b1,
    const float* __restrict__ w2, const float* __restrict__ b2,
    double* __restrict__ theta) {
  int b = blockIdx.x;
  __shared__ double h1[32];
  if (threadIdx.x < 32) {
    double v = (double)b1[threadIdx.x];
#pragma unroll
    for (int q = 0; q < 8; ++q) v += part[((size_t)b * 8 + q) * 32 + threadIdx.x];
    h1[threadIdx.x] = v > 0.0 ? v : 0.0;
  }
  __syncthreads();
  if (threadIdx.x < 6) {
    double v = (double)b2[threadIdx.x];
#pragma unroll
    for (int k = 0; k < 32; ++k) v += h1[k] * (double)w2[k * 6 + threadIdx.x];
    theta[b * 6 + threadIdx.x] = v;
  }
}

// affine grid + bilinear sampler, reference-exact (incl. extrapolation quirk).
__global__ __launch_bounds__(256) void k_sample(
    const float* __restrict__ img, const double* __restrict__ theta,
    float* __restrict__ out) {
  int idx = blockIdx.x * 256 + threadIdx.x;
  if (idx >= 64 * 224 * 224) return;
  int x = idx % 224;
  int t = idx / 224;
  int y = t % 224;
  int b = t / 224;

  const double* th = theta + b * 6;
  double t0 = th[0], t1 = th[1], t2 = th[2];
  double t3 = th[3], t4 = th[4], t5 = th[5];

  double xn = -1.0 + x * (2.0 / 223.0);
  double yn = -1.0 + y * (2.0 / 223.0);
  double xf = 0.5 * (t0 * xn + t1 * yn + t2 + 1.0) * 223.0;
  double yf = 0.5 * (t3 * xn + t4 * yn + t5 + 1.0) * 223.0;

  int x0 = (int)floor(xf);
  int y0 = (int)floor(yf);
  x0 = min(max(x0, 0), 223);
  y0 = min(max(y0, 0), 223);
  int x1 = min(x0 + 1, 223);
  int y1 = min(y0 + 1, 223);

  double x0f = (double)x0, x1f = (double)x1;
  double y0f = (double)y0, y1f = (double)y1;
  // weights from UNCLIPPED xf/yf — reference semantics (extrapolates)
  double wa = (x1f - xf) * (y1f - yf);
  double wb = (x1f - xf) * (yf - y0f);
  double wc = (xf - x0f) * (y1f - yf);
  double wd = (xf - x0f) * (yf - y0f);

  const float* p = img + (size_t)b * 150528;
  const float* Ia = p + ((size_t)y0 * 224 + x0) * 3;
  const float* Ib = p + ((size_t)y1 * 224 + x0) * 3;
  const float* Ic = p + ((size_t)y0 * 224 + x1) * 3;
  const float* Id = p + ((size_t)y1 * 224 + x1) * 3;

  float* op = out + (size_t)idx * 3;
#pragma unroll
  for (int c = 0; c < 3; ++c) {
    op[c] = (float)(wa * (double)Ia[c] + wb * (double)Ib[c] +
                    wc * (double)Ic[c] + wd * (double)Id[c]);
  }
}

extern "C" void kernel_launch(void* const* d_in, const int* in_sizes, int n_in,
                              void* d_out, int out_size, void* d_ws, size_t ws_size,
                              hipStream_t stream) {
  const float* inputs  = (const float*)d_in[0];  // (64,224,224,3)
  const float* conv1_w = (const float*)d_in[1];  // (7,7,3,8)
  const float* conv1_b = (const float*)d_in[2];  // (8)
  const float* conv2_w = (const float*)d_in[3];  // (5,5,8,10)
  const float* conv2_b = (const float*)d_in[4];  // (10)
  const float* fc1_w   = (const float*)d_in[5];  // (27040,32)
  const float* fc1_b   = (const float*)d_in[6];  // (32)
  const float* fc2_w   = (const float*)d_in[7];  // (32,6)
  const float* fc2_b   = (const float*)d_in[8];  // (6)
  float* outp = (float*)d_out;                   // (64,224,224,3)

  // ws layout (16B aligned): theta | fc partials | pool1 f64 | pool2 f64
  double* theta = (double*)d_ws;                       // 64*6
  double* part  = (double*)((char*)d_ws + 4096);       // 64*8*32 = 16384 d
  double* pool1 = (double*)((char*)d_ws + 4096 + 131072);  // 6,081,152 d
  double* pool2 = pool1 + 6081152;                     // 1,730,560 d

  // Stage 1: 55 tiles/batch * 64 batches, XCD-grouped
  k_conv1<<<55 * 64, 256, 0, stream>>>(inputs, conv1_w, conv1_b, pool1);
  // Stage 2: 26 tiles/batch * 64 batches, XCD-grouped
  k_conv2<<<26 * 64, 256, 0, stream>>>(pool1, conv2_w, conv2_b, pool2);
  // Stage 3
  k_fc1<<<512, 256, 0, stream>>>(pool2, fc1_w, part);
  k_fc2<<<64, 64, 0, stream>>>(part, fc1_b, fc2_w, fc2_b, theta);
  // Stage 4
  k_sample<<<(64 * 224 * 224 + 255) / 256, 256, 0, stream>>>(inputs, theta, outp);
}

// Round 8
// 428.726 us; speedup vs baseline: 3.0630x; 1.1114x over previous
//
#include <hip/hip_runtime.h>

// ---------------------------------------------------------------------------
// STN pipeline, theta chain in FP64 (must match np float64 reference: sampler
// has floor() discontinuities at coord==223 with O(100..1000) jumps; f32
// noise upstream of theta flips floors -> fails. Any-order f64 lands ~1e-13
// from the np value -> flip set identical -> absmax stays ~73).
//
// R8: lane-utilization + bank-conflict round.
//  - conv1: flat-256 row-major pixel tiles (was 2x109=218/256 lanes=85%).
//    Tile spans <=4 pooled rows -> stage 14-row f32 band (47 KB LDS total).
//  - conv2: flat tiles (pix,oh) pairs (was 208/256=81%), and channel-planar
//    LDS band [cc][12][112] killing the 16-way bank conflicts of [rr][x][cc]
//    (lane stride was 64 B = 2 banks).
// ---------------------------------------------------------------------------

// conv1 + relu + maxpool : in (64,224,224,3) f32 -> out (64,109,109,8) f64
// Block: 256 consecutive row-major pooled pixels of one batch.
__global__ __launch_bounds__(256) void k_conv1(
    const float* __restrict__ in, const float* __restrict__ w,
    const float* __restrict__ bias, double* __restrict__ out) {
  __shared__ float win[14 * 672];   // 14 input rows x 224*3
  __shared__ double sw[147 * 8];    // [tap(ky,kx,c)][oc]
  __shared__ double sb[8];
  for (int i = threadIdx.x; i < 1176; i += 256) sw[i] = (double)w[i];
  if (threadIdx.x < 8) sb[threadIdx.x] = (double)bias[threadIdx.x];

  // XCD swizzle: 47 tiles/batch, 8 batches/group.
  int g = blockIdx.x & 7;
  int i = blockIdx.x >> 3;          // 0..375
  int b = g * 8 + i / 47;
  int tile = i % 47;
  int p0 = tile * 256;              // first pooled pixel (row-major, 109x109)
  int py0 = p0 / 109;
  int r0 = 2 * py0;                 // first input row of the band

  // stage 14 input rows (row clamped to 223), full width, as float4
  {
    const float* ibb = in + (size_t)b * 150528;
    for (int idx = threadIdx.x; idx < 14 * 168; idx += 256) {
      int rr = idx / 168, c4 = idx % 168;
      int row = min(r0 + rr, 223);
      float4 v = reinterpret_cast<const float4*>(ibb + (size_t)row * 672)[c4];
      reinterpret_cast<float4*>(&win[rr * 672])[c4] = v;
    }
  }
  __syncthreads();

  int pix = p0 + threadIdx.x;
  if (pix < 11881) {
    int px = pix % 109;
    int py = pix / 109;
    int lrb = 2 * py - r0;          // 0,2,4,6

    double acc[2][2][8];
#pragma unroll
    for (int ii = 0; ii < 2; ++ii)
#pragma unroll
      for (int j = 0; j < 2; ++j)
#pragma unroll
        for (int k = 0; k < 8; ++k) acc[ii][j][k] = 0.0;

    for (int ky = 0; ky < 7; ++ky) {
      const float* r0p = &win[(lrb + ky) * 672 + 6 * px];
      const float* r1p = r0p + 672;
      float a0[24], a1[24];
#pragma unroll
      for (int j = 0; j < 12; ++j) {
        float2 u = reinterpret_cast<const float2*>(r0p)[j];
        a0[2 * j] = u.x; a0[2 * j + 1] = u.y;
        float2 v = reinterpret_cast<const float2*>(r1p)[j];
        a1[2 * j] = v.x; a1[2 * j + 1] = v.y;
      }
#pragma unroll
      for (int kx = 0; kx < 7; ++kx) {
#pragma unroll
        for (int c = 0; c < 3; ++c) {
          double v00 = (double)a0[kx * 3 + c];
          double v01 = (double)a0[kx * 3 + 3 + c];
          double v10 = (double)a1[kx * 3 + c];
          double v11 = (double)a1[kx * 3 + 3 + c];
          const double* wp = &sw[((ky * 7 + kx) * 3 + c) * 8];
#pragma unroll
          for (int oc = 0; oc < 8; ++oc) {
            double wv = wp[oc];
            acc[0][0][oc] = fma(v00, wv, acc[0][0][oc]);
            acc[0][1][oc] = fma(v01, wv, acc[0][1][oc]);
            acc[1][0][oc] = fma(v10, wv, acc[1][0][oc]);
            acc[1][1][oc] = fma(v11, wv, acc[1][1][oc]);
          }
        }
      }
    }

    double* op = out + ((size_t)b * 11881 + pix) * 8;
#pragma unroll
    for (int oc = 0; oc < 8; ++oc) {
      double m = fmax(fmax(acc[0][0][oc], acc[0][1][oc]),
                      fmax(acc[1][0][oc], acc[1][1][oc]));
      op[oc] = fmax(m + sb[oc], 0.0);
    }
  }
}

// conv2 + relu + maxpool : in (64,109,109,8) f64 -> out (64,52,52,10) f64
// Work item = (pooled pixel, oc-half); 256 consecutive items per block ->
// 128 consecutive pixels (<=4 pooled rows -> 12-row band). Channel-planar
// LDS band win2[cc][12][112]; two channel-half passes.
__global__ __launch_bounds__(256) void k_conv2(
    const double* __restrict__ in, const float* __restrict__ w,
    const float* __restrict__ bias, double* __restrict__ out) {
  __shared__ double win2[4 * 12 * 112];  // [cc][rr][x]
  __shared__ double sw[200 * 12];        // [tap(ky,kx,c)][oh*6+oc]
  __shared__ double sb[10];
  for (int i = threadIdx.x; i < 2000; i += 256) {
    int tap = i / 10, oc = i % 10;
    sw[tap * 12 + (oc / 5) * 6 + (oc % 5)] = (double)w[i];
  }
  if (threadIdx.x < 10) sb[threadIdx.x] = (double)bias[threadIdx.x];

  // XCD swizzle: 22 tiles/batch (5408 work items / 256), 8 batches/group.
  int g = blockIdx.x & 7;
  int i = blockIdx.x >> 3;          // 0..175
  int b = g * 8 + i / 22;
  int tile = i % 22;
  int wi = tile * 256 + threadIdx.x;
  bool valid = wi < 5408;
  int oh = wi & 1;
  int pix = wi >> 1;                // block covers pixels [tile*128, +127]
  int p0 = tile * 128;
  int py0 = p0 / 52;
  int r0 = 2 * py0;                 // first conv2-input row of band (12 rows)

  int px = pix % 52;
  int py = pix / 52;
  int lrb = 2 * py - r0;            // 0,2,4,6

  double acc[2][2][5];
#pragma unroll
  for (int ii = 0; ii < 2; ++ii)
#pragma unroll
    for (int jj = 0; jj < 2; ++jj)
#pragma unroll
      for (int k = 0; k < 5; ++k) acc[ii][jj][k] = 0.0;

  const double* ib = in + (size_t)b * 11881 * 8;

  for (int h = 0; h < 2; ++h) {
    __syncthreads();  // protects win2 reuse + first-pass weight staging
    // stage 12 rows x 109 x channels [h*4..h*4+3] into planar layout
    for (int idx = threadIdx.x; idx < 12 * 109 * 2; idx += 256) {
      int d2 = idx & 1;               // channel pair (0-1 / 2-3)
      int x  = (idx >> 1) % 109;
      int rr = (idx >> 1) / 109;
      int row = min(r0 + rr, 108);
      double2 v = *reinterpret_cast<const double2*>(
          ib + ((size_t)row * 109 + x) * 8 + h * 4 + d2 * 2);
      win2[((d2 * 2) * 12 + rr) * 112 + x] = v.x;
      win2[((d2 * 2 + 1) * 12 + rr) * 112 + x] = v.y;
    }
    __syncthreads();

    if (valid) {
#pragma unroll
      for (int ky = 0; ky < 5; ++ky) {
        int rr0 = lrb + ky;
#pragma unroll
        for (int kx = 0; kx < 5; ++kx) {
          int xx = 2 * px + kx;
#pragma unroll
          for (int cc = 0; cc < 4; ++cc) {
            int c = h * 4 + cc;
            const double* pbase = &win2[(cc * 12 + rr0) * 112 + xx];
            double v00 = pbase[0];
            double v01 = pbase[1];
            double v10 = pbase[112];
            double v11 = pbase[113];
            const double* wp = &sw[((ky * 5 + kx) * 8 + c) * 12 + oh * 6];
#pragma unroll
            for (int oc = 0; oc < 5; ++oc) {
              double wv = wp[oc];
              acc[0][0][oc] = fma(v00, wv, acc[0][0][oc]);
              acc[0][1][oc] = fma(v01, wv, acc[0][1][oc]);
              acc[1][0][oc] = fma(v10, wv, acc[1][0][oc]);
              acc[1][1][oc] = fma(v11, wv, acc[1][1][oc]);
            }
          }
        }
      }
    }
  }

  if (valid) {
    double* op = out + ((size_t)b * 2704 + pix) * 10 + oh * 5;
#pragma unroll
    for (int oc = 0; oc < 5; ++oc) {
      double m = fmax(fmax(acc[0][0][oc], acc[0][1][oc]),
                      fmax(acc[1][0][oc], acc[1][1][oc]));
      op[oc] = fmax(m + sb[oh * 5 + oc], 0.0);
    }
  }
}

// fc1 partial dots: grid 512 = (64 b) x (8 q); block 256 = 32 oc x 8 strips.
__global__ __launch_bounds__(256) void k_fc1(
    const double* __restrict__ xs, const float* __restrict__ w1,
    double* __restrict__ part) {
  int b = blockIdx.x >> 3;
  int q = blockIdx.x & 7;
  int oc = threadIdx.x & 31;
  int s = threadIdx.x >> 5;
  const double* xrow = xs + (size_t)b * 27040;

  int i0 = q * 3392 + s * 424;
  int i1 = min(i0 + 424, 27040);
  double s0 = 0.0, s1 = 0.0;
  for (int i = i0; i + 1 < i1; i += 2) {
    s0 = fma(xrow[i],     (double)w1[(size_t)i * 32 + oc],       s0);
    s1 = fma(xrow[i + 1], (double)w1[(size_t)(i + 1) * 32 + oc], s1);
  }
  if (((i1 - i0) & 1) && i0 < i1)
    s0 = fma(xrow[i1 - 1], (double)w1[(size_t)(i1 - 1) * 32 + oc], s0);

  __shared__ double red[8][32];
  red[s][oc] = s0 + s1;
  __syncthreads();
  if (threadIdx.x < 32) {
    double v = 0.0;
#pragma unroll
    for (int k = 0; k < 8; ++k) v += red[k][threadIdx.x];
    part[((size_t)b * 8 + q) * 32 + threadIdx.x] = v;
  }
}

// fc1 reduce + ReLU + fc2 -> theta. 64 blocks x 64 threads.
__global__ __launch_bounds__(64) void k_fc2(
    const double* __restrict__ part, const float* __restrict__ b1,
    const float* __restrict__ w2, const float* __restrict__ b2,
    double* __restrict__ theta) {
  int b = blockIdx.x;
  __shared__ double h1[32];
  if (threadIdx.x < 32) {
    double v = (double)b1[threadIdx.x];
#pragma unroll
    for (int q = 0; q < 8; ++q) v += part[((size_t)b * 8 + q) * 32 + threadIdx.x];
    h1[threadIdx.x] = v > 0.0 ? v : 0.0;
  }
  __syncthreads();
  if (threadIdx.x < 6) {
    double v = (double)b2[threadIdx.x];
#pragma unroll
    for (int k = 0; k < 32; ++k) v += h1[k] * (double)w2[k * 6 + threadIdx.x];
    theta[b * 6 + threadIdx.x] = v;
  }
}

// affine grid + bilinear sampler, reference-exact (incl. extrapolation quirk).
__global__ __launch_bounds__(256) void k_sample(
    const float* __restrict__ img, const double* __restrict__ theta,
    float* __restrict__ out) {
  int idx = blockIdx.x * 256 + threadIdx.x;
  if (idx >= 64 * 224 * 224) return;
  int x = idx % 224;
  int t = idx / 224;
  int y = t % 224;
  int b = t / 224;

  const double* th = theta + b * 6;
  double t0 = th[0], t1 = th[1], t2 = th[2];
  double t3 = th[3], t4 = th[4], t5 = th[5];

  double xn = -1.0 + x * (2.0 / 223.0);
  double yn = -1.0 + y * (2.0 / 223.0);
  double xf = 0.5 * (t0 * xn + t1 * yn + t2 + 1.0) * 223.0;
  double yf = 0.5 * (t3 * xn + t4 * yn + t5 + 1.0) * 223.0;

  int x0 = (int)floor(xf);
  int y0 = (int)floor(yf);
  x0 = min(max(x0, 0), 223);
  y0 = min(max(y0, 0), 223);
  int x1 = min(x0 + 1, 223);
  int y1 = min(y0 + 1, 223);

  double x0f = (double)x0, x1f = (double)x1;
  double y0f = (double)y0, y1f = (double)y1;
  // weights from UNCLIPPED xf/yf — reference semantics (extrapolates)
  double wa = (x1f - xf) * (y1f - yf);
  double wb = (x1f - xf) * (yf - y0f);
  double wc = (xf - x0f) * (y1f - yf);
  double wd = (xf - x0f) * (yf - y0f);

  const float* p = img + (size_t)b * 150528;
  const float* Ia = p + ((size_t)y0 * 224 + x0) * 3;
  const float* Ib = p + ((size_t)y1 * 224 + x0) * 3;
  const float* Ic = p + ((size_t)y0 * 224 + x1) * 3;
  const float* Id = p + ((size_t)y1 * 224 + x1) * 3;

  float* op = out + (size_t)idx * 3;
#pragma unroll
  for (int c = 0; c < 3; ++c) {
    op[c] = (float)(wa * (double)Ia[c] + wb * (double)Ib[c] +
                    wc * (double)Ic[c] + wd * (double)Id[c]);
  }
}

extern "C" void kernel_launch(void* const* d_in, const int* in_sizes, int n_in,
                              void* d_out, int out_size, void* d_ws, size_t ws_size,
                              hipStream_t stream) {
  const float* inputs  = (const float*)d_in[0];  // (64,224,224,3)
  const float* conv1_w = (const float*)d_in[1];  // (7,7,3,8)
  const float* conv1_b = (const float*)d_in[2];  // (8)
  const float* conv2_w = (const float*)d_in[3];  // (5,5,8,10)
  const float* conv2_b = (const float*)d_in[4];  // (10)
  const float* fc1_w   = (const float*)d_in[5];  // (27040,32)
  const float* fc1_b   = (const float*)d_in[6];  // (32)
  const float* fc2_w   = (const float*)d_in[7];  // (32,6)
  const float* fc2_b   = (const float*)d_in[8];  // (6)
  float* outp = (float*)d_out;                   // (64,224,224,3)

  // ws layout (16B aligned): theta | fc partials | pool1 f64 | pool2 f64
  double* theta = (double*)d_ws;                       // 64*6
  double* part  = (double*)((char*)d_ws + 4096);       // 64*8*32
  double* pool1 = (double*)((char*)d_ws + 4096 + 131072);  // 6,081,152 d
  double* pool2 = pool1 + 6081152;                     // 1,730,560 d

  // Stage 1: 47 tiles/batch * 64 batches, XCD-grouped
  k_conv1<<<47 * 64, 256, 0, stream>>>(inputs, conv1_w, conv1_b, pool1);
  // Stage 2: 22 tiles/batch * 64 batches, XCD-grouped
  k_conv2<<<22 * 64, 256, 0, stream>>>(pool1, conv2_w, conv2_b, pool2);
  // Stage 3
  k_fc1<<<512, 256, 0, stream>>>(pool2, fc1_w, part);
  k_fc2<<<64, 64, 0, stream>>>(part, fc1_b, fc2_w, fc2_b, theta);
  // Stage 4
  k_sample<<<(64 * 224 * 224 + 255) / 256, 256, 0, stream>>>(inputs, theta, outp);
}

// Round 9
// 392.448 us; speedup vs baseline: 3.3462x; 1.0924x over previous
//
#include <hip/hip_runtime.h>

// ---------------------------------------------------------------------------
// STN pipeline, theta chain in FP64 (must match np float64 reference: sampler
// has floor() discontinuities at coord==223 with O(100..1000) jumps; f32
// noise upstream of theta flips floors -> fails. Any-order f64 lands ~1e-13
// from the np value -> flip set identical -> absmax stays ~73).
//
// R9: occupancy round. R7/R8 showed VALUBusy tracks waves/CU (9.3w->76%,
// 6.3w->67%). Same LDS band now serves 7 waves instead of 4:
//  - conv1: 448-thread blocks, 4 pooled rows/tile (436/448 lanes), 14-row
//    47KB band -> 3 blocks/CU x 7 waves ~ 20 waves/CU.
//  - conv2: 448-thread blocks, 4 pooled rows/tile (416/448), 12-row planar
//    band (41.9KB) + packed weights -> 2 blocks/CU x 7 = 14 waves/CU.
//    13 tiles/batch divides 52 exactly (no ragged tiles).
//  - fc1: grid 1024 (16 q-chunks) for better spread.
// ---------------------------------------------------------------------------

// conv1 + relu + maxpool : in (64,224,224,3) f32 -> out (64,109,109,8) f64
// Block: 4 pooled rows x 109 px (436 work items on 448 threads).
__global__ __launch_bounds__(448) void k_conv1(
    const float* __restrict__ in, const float* __restrict__ w,
    const float* __restrict__ bias, double* __restrict__ out) {
  __shared__ float win[14 * 672];   // 14 input rows x 224*3
  __shared__ double sw[147 * 8];    // [tap(ky,kx,c)][oc]
  __shared__ double sb[8];
  for (int i = threadIdx.x; i < 1176; i += 448) sw[i] = (double)w[i];
  if (threadIdx.x < 8) sb[threadIdx.x] = (double)bias[threadIdx.x];

  // XCD swizzle: 28 tiles/batch, 8 batches/group (group pinned to one XCD).
  int g = blockIdx.x & 7;
  int i = blockIdx.x >> 3;          // 0..223
  int b = g * 8 + i / 28;
  int tile = i % 28;
  int py0 = 4 * tile;               // first pooled row (last tile: 108 only)
  int r0 = 8 * tile;                // first input row of the 14-row band

  // stage 14 input rows (row clamped to 223), full width, as float4
  {
    const float* ibb = in + (size_t)b * 150528;
    for (int idx = threadIdx.x; idx < 14 * 168; idx += 448) {
      int rr = idx / 168, c4 = idx % 168;
      int row = min(r0 + rr, 223);
      float4 v = reinterpret_cast<const float4*>(ibb + (size_t)row * 672)[c4];
      reinterpret_cast<float4*>(&win[rr * 672])[c4] = v;
    }
  }
  __syncthreads();

  int t = threadIdx.x;
  int py = py0 + t / 109;
  if (t < 436 && py < 109) {
    int px = t % 109;
    int lrb = 2 * (t / 109);        // 0,2,4,6

    double acc[2][2][8];
#pragma unroll
    for (int ii = 0; ii < 2; ++ii)
#pragma unroll
      for (int j = 0; j < 2; ++j)
#pragma unroll
        for (int k = 0; k < 8; ++k) acc[ii][j][k] = 0.0;

    for (int ky = 0; ky < 7; ++ky) {
      const float* r0p = &win[(lrb + ky) * 672 + 6 * px];
      const float* r1p = r0p + 672;
      float a0[24], a1[24];
#pragma unroll
      for (int j = 0; j < 12; ++j) {
        float2 u = reinterpret_cast<const float2*>(r0p)[j];
        a0[2 * j] = u.x; a0[2 * j + 1] = u.y;
        float2 v = reinterpret_cast<const float2*>(r1p)[j];
        a1[2 * j] = v.x; a1[2 * j + 1] = v.y;
      }
#pragma unroll
      for (int kx = 0; kx < 7; ++kx) {
#pragma unroll
        for (int c = 0; c < 3; ++c) {
          double v00 = (double)a0[kx * 3 + c];
          double v01 = (double)a0[kx * 3 + 3 + c];
          double v10 = (double)a1[kx * 3 + c];
          double v11 = (double)a1[kx * 3 + 3 + c];
          const double* wp = &sw[((ky * 7 + kx) * 3 + c) * 8];
#pragma unroll
          for (int oc = 0; oc < 8; ++oc) {
            double wv = wp[oc];
            acc[0][0][oc] = fma(v00, wv, acc[0][0][oc]);
            acc[0][1][oc] = fma(v01, wv, acc[0][1][oc]);
            acc[1][0][oc] = fma(v10, wv, acc[1][0][oc]);
            acc[1][1][oc] = fma(v11, wv, acc[1][1][oc]);
          }
        }
      }
    }

    double* op = out + ((size_t)b * 11881 + (size_t)py * 109 + px) * 8;
#pragma unroll
    for (int oc = 0; oc < 8; ++oc) {
      double m = fmax(fmax(acc[0][0][oc], acc[0][1][oc]),
                      fmax(acc[1][0][oc], acc[1][1][oc]));
      op[oc] = fmax(m + sb[oc], 0.0);
    }
  }
}

// conv2 + relu + maxpool : in (64,109,109,8) f64 -> out (64,52,52,10) f64
// Block: 4 pooled rows; items = 208 px x 2 oc-halves = 416 on 448 threads.
// Channel-planar band win2[cc][12][112]; two channel-half passes.
__global__ __launch_bounds__(448) void k_conv2(
    const double* __restrict__ in, const float* __restrict__ w,
    const float* __restrict__ bias, double* __restrict__ out) {
  __shared__ double win2[4 * 12 * 112];  // [cc][rr][x]
  __shared__ double sw[200 * 12];        // [tap(ky,kx,c)][oh*6+oc]
  __shared__ double sb[10];
  for (int i = threadIdx.x; i < 2000; i += 448) {
    int tap = i / 10, oc = i % 10;
    sw[tap * 12 + (oc / 5) * 6 + (oc % 5)] = (double)w[i];
  }
  if (threadIdx.x < 10) sb[threadIdx.x] = (double)bias[threadIdx.x];

  // XCD swizzle: 13 tiles/batch (52/4 exact), 8 batches/group.
  int g = blockIdx.x & 7;
  int i = blockIdx.x >> 3;          // 0..103
  int b = g * 8 + i / 13;
  int tile = i % 13;
  int py0 = 4 * tile;
  int r0 = 8 * tile;                // first conv2-input row; 12-row band,
                                    // max row = 8*12+11 = 107 <= 108 (no clamp)

  int t = threadIdx.x;
  bool valid = t < 416;
  int oh = t & 1;
  int p = t >> 1;                   // 0..207 within tile
  int px = p % 52;
  int lrb = 2 * (p / 52);           // 0,2,4,6

  double acc[2][2][5];
#pragma unroll
  for (int ii = 0; ii < 2; ++ii)
#pragma unroll
    for (int jj = 0; jj < 2; ++jj)
#pragma unroll
      for (int k = 0; k < 5; ++k) acc[ii][jj][k] = 0.0;

  const double* ib = in + (size_t)b * 11881 * 8;

  for (int h = 0; h < 2; ++h) {
    __syncthreads();  // protects win2 reuse + first-pass weight staging
    // stage 12 rows x 109 x channels [h*4..h*4+3] into planar layout
    for (int idx = threadIdx.x; idx < 12 * 109 * 2; idx += 448) {
      int d2 = idx & 1;               // channel pair (0-1 / 2-3)
      int x  = (idx >> 1) % 109;
      int rr = (idx >> 1) / 109;
      double2 v = *reinterpret_cast<const double2*>(
          ib + ((size_t)(r0 + rr) * 109 + x) * 8 + h * 4 + d2 * 2);
      win2[((d2 * 2) * 12 + rr) * 112 + x] = v.x;
      win2[((d2 * 2 + 1) * 12 + rr) * 112 + x] = v.y;
    }
    __syncthreads();

    if (valid) {
#pragma unroll
      for (int ky = 0; ky < 5; ++ky) {
        int rr0 = lrb + ky;
#pragma unroll
        for (int kx = 0; kx < 5; ++kx) {
          int xx = 2 * px + kx;
#pragma unroll
          for (int cc = 0; cc < 4; ++cc) {
            int c = h * 4 + cc;
            const double* pbase = &win2[(cc * 12 + rr0) * 112 + xx];
            double v00 = pbase[0];
            double v01 = pbase[1];
            double v10 = pbase[112];
            double v11 = pbase[113];
            const double* wp = &sw[((ky * 5 + kx) * 8 + c) * 12 + oh * 6];
#pragma unroll
            for (int oc = 0; oc < 5; ++oc) {
              double wv = wp[oc];
              acc[0][0][oc] = fma(v00, wv, acc[0][0][oc]);
              acc[0][1][oc] = fma(v01, wv, acc[0][1][oc]);
              acc[1][0][oc] = fma(v10, wv, acc[1][0][oc]);
              acc[1][1][oc] = fma(v11, wv, acc[1][1][oc]);
            }
          }
        }
      }
    }
  }

  if (valid) {
    int pix = py0 * 52 + p;           // p already row-major within tile
    double* op = out + ((size_t)b * 2704 + pix) * 10 + oh * 5;
#pragma unroll
    for (int oc = 0; oc < 5; ++oc) {
      double m = fmax(fmax(acc[0][0][oc], acc[0][1][oc]),
                      fmax(acc[1][0][oc], acc[1][1][oc]));
      op[oc] = fmax(m + sb[oh * 5 + oc], 0.0);
    }
  }
}

// fc1 partial dots: grid 1024 = (64 b) x (16 q); block 256 = 32 oc x 8 strips.
__global__ __launch_bounds__(256) void k_fc1(
    const double* __restrict__ xs, const float* __restrict__ w1,
    double* __restrict__ part) {
  int b = blockIdx.x >> 4;
  int q = blockIdx.x & 15;
  int oc = threadIdx.x & 31;
  int s = threadIdx.x >> 5;
  const double* xrow = xs + (size_t)b * 27040;

  int i0 = q * 1690 + s * 212;
  int i1 = min(i0 + 212, q * 1690 + 1690);
  double s0 = 0.0, s1 = 0.0;
  for (int i = i0; i + 1 < i1; i += 2) {
    s0 = fma(xrow[i],     (double)w1[(size_t)i * 32 + oc],       s0);
    s1 = fma(xrow[i + 1], (double)w1[(size_t)(i + 1) * 32 + oc], s1);
  }
  if ((i1 - i0) & 1)
    s0 = fma(xrow[i1 - 1], (double)w1[(size_t)(i1 - 1) * 32 + oc], s0);

  __shared__ double red[8][32];
  red[s][oc] = s0 + s1;
  __syncthreads();
  if (threadIdx.x < 32) {
    double v = 0.0;
#pragma unroll
    for (int k = 0; k < 8; ++k) v += red[k][threadIdx.x];
    part[((size_t)b * 16 + q) * 32 + threadIdx.x] = v;
  }
}

// fc1 reduce + ReLU + fc2 -> theta. 64 blocks x 64 threads.
__global__ __launch_bounds__(64) void k_fc2(
    const double* __restrict__ part, const float* __restrict__ b1,
    const float* __restrict__ w2, const float* __restrict__ b2,
    double* __restrict__ theta) {
  int b = blockIdx.x;
  __shared__ double h1[32];
  if (threadIdx.x < 32) {
    double v = (double)b1[threadIdx.x];
#pragma unroll
    for (int q = 0; q < 16; ++q)
      v += part[((size_t)b * 16 + q) * 32 + threadIdx.x];
    h1[threadIdx.x] = v > 0.0 ? v : 0.0;
  }
  __syncthreads();
  if (threadIdx.x < 6) {
    double v = (double)b2[threadIdx.x];
#pragma unroll
    for (int k = 0; k < 32; ++k) v += h1[k] * (double)w2[k * 6 + threadIdx.x];
    theta[b * 6 + threadIdx.x] = v;
  }
}

// affine grid + bilinear sampler, reference-exact (incl. extrapolation quirk).
__global__ __launch_bounds__(256) void k_sample(
    const float* __restrict__ img, const double* __restrict__ theta,
    float* __restrict__ out) {
  int idx = blockIdx.x * 256 + threadIdx.x;
  if (idx >= 64 * 224 * 224) return;
  int x = idx % 224;
  int t = idx / 224;
  int y = t % 224;
  int b = t / 224;

  const double* th = theta + b * 6;
  double t0 = th[0], t1 = th[1], t2 = th[2];
  double t3 = th[3], t4 = th[4], t5 = th[5];

  double xn = -1.0 + x * (2.0 / 223.0);
  double yn = -1.0 + y * (2.0 / 223.0);
  double xf = 0.5 * (t0 * xn + t1 * yn + t2 + 1.0) * 223.0;
  double yf = 0.5 * (t3 * xn + t4 * yn + t5 + 1.0) * 223.0;

  int x0 = (int)floor(xf);
  int y0 = (int)floor(yf);
  x0 = min(max(x0, 0), 223);
  y0 = min(max(y0, 0), 223);
  int x1 = min(x0 + 1, 223);
  int y1 = min(y0 + 1, 223);

  double x0f = (double)x0, x1f = (double)x1;
  double y0f = (double)y0, y1f = (double)y1;
  // weights from UNCLIPPED xf/yf — reference semantics (extrapolates)
  double wa = (x1f - xf) * (y1f - yf);
  double wb = (x1f - xf) * (yf - y0f);
  double wc = (xf - x0f) * (y1f - yf);
  double wd = (xf - x0f) * (yf - y0f);

  const float* p = img + (size_t)b * 150528;
  const float* Ia = p + ((size_t)y0 * 224 + x0) * 3;
  const float* Ib = p + ((size_t)y1 * 224 + x0) * 3;
  const float* Ic = p + ((size_t)y0 * 224 + x1) * 3;
  const float* Id = p + ((size_t)y1 * 224 + x1) * 3;

  float* op = out + (size_t)idx * 3;
#pragma unroll
  for (int c = 0; c < 3; ++c) {
    op[c] = (float)(wa * (double)Ia[c] + wb * (double)Ib[c] +
                    wc * (double)Ic[c] + wd * (double)Id[c]);
  }
}

extern "C" void kernel_launch(void* const* d_in, const int* in_sizes, int n_in,
                              void* d_out, int out_size, void* d_ws, size_t ws_size,
                              hipStream_t stream) {
  const float* inputs  = (const float*)d_in[0];  // (64,224,224,3)
  const float* conv1_w = (const float*)d_in[1];  // (7,7,3,8)
  const float* conv1_b = (const float*)d_in[2];  // (8)
  const float* conv2_w = (const float*)d_in[3];  // (5,5,8,10)
  const float* conv2_b = (const float*)d_in[4];  // (10)
  const float* fc1_w   = (const float*)d_in[5];  // (27040,32)
  const float* fc1_b   = (const float*)d_in[6];  // (32)
  const float* fc2_w   = (const float*)d_in[7];  // (32,6)
  const float* fc2_b   = (const float*)d_in[8];  // (6)
  float* outp = (float*)d_out;                   // (64,224,224,3)

  // ws layout (16B aligned): theta | fc partials | pool1 f64 | pool2 f64
  double* theta = (double*)d_ws;                       // 64*6
  double* part  = (double*)((char*)d_ws + 4096);       // 64*16*32
  double* pool1 = (double*)((char*)d_ws + 4096 + 262144);  // 6,081,152 d
  double* pool2 = pool1 + 6081152;                     // 1,730,560 d

  // Stage 1: 28 tiles/batch * 64 batches (448-thread blocks), XCD-grouped
  k_conv1<<<28 * 64, 448, 0, stream>>>(inputs, conv1_w, conv1_b, pool1);
  // Stage 2: 13 tiles/batch * 64 batches (448-thread blocks), XCD-grouped
  k_conv2<<<13 * 64, 448, 0, stream>>>(pool1, conv2_w, conv2_b, pool2);
  // Stage 3
  k_fc1<<<1024, 256, 0, stream>>>(pool2, fc1_w, part);
  k_fc2<<<64, 64, 0, stream>>>(part, fc1_b, fc2_w, fc2_b, theta);
  // Stage 4
  k_sample<<<(64 * 224 * 224 + 255) / 256, 256, 0, stream>>>(inputs, theta, outp);
}